// Round 2
// baseline (935.269 us; speedup 1.0000x reference)
//
#include <hip/hip_runtime.h>
#include <hip/hip_bf16.h>

// LSTMblock: 2-layer, 8-head LSTM (H=F=64, T=12) over N=16384 independent
// nodes, then 1x1 conv mixing (head,t) channels (96 -> 12).
//
// Structure: every node independent; layer1 step t needs only layer0 h at t.
// One workgroup per 16-node tile runs both layers in lockstep over t, loops
// heads, accumulates the 12 conv outputs in registers. Single fused pass.
//
// R2: input dtype is ambiguous (reference says fp32; test labels say bf16 but
// the label is hardcoded in the test source). R1's all-NaN output is the
// signature of reading fp32 bits as bf16 (random exponent fields -> Inf/NaN
// weights). This round: a 1-thread detector kernel classifies the dtype from
// x's bit patterns into a flag in d_ws; the main kernel takes a wave-uniform
// branch into a float- or bf16-load specialization. Compute path identical:
// bf16 MFMA fragments, fp32 cell math.
//
// MFMA v_mfma_f32_16x16x32_bf16 lane mapping (m89/m120-verified):
//   A[m][k]: lane(quad,col) reg j holds A[m=col][k=quad*8+j]
//   B[k][n]: lane reg j holds B[k=quad*8+j][n=col]
//   D[m][n]: lane reg r holds D[m=quad*4+r][n=col]

#define T_LEN 12
#define NHEADS 8
#define HD 64
#define NNODES 16384
#define MT 16
#define LDSP 72

typedef __bf16 bf16_t;
typedef __attribute__((ext_vector_type(8))) __bf16 bf16x8;
typedef __attribute__((ext_vector_type(4))) float f32x4;

#define MFMA16(a, b, c) __builtin_amdgcn_mfma_f32_16x16x32_bf16((a), (b), (c), 0, 0, 0)

__device__ __forceinline__ float fast_sigmoid(float v) {
    return __builtin_amdgcn_rcpf(1.0f + __expf(-v));
}
__device__ __forceinline__ float fast_tanh(float v) {
    return 2.0f * __builtin_amdgcn_rcpf(1.0f + __expf(-2.0f * v)) - 1.0f;
}

// ---- dtype-polymorphic loads/stores ----
template <typename T> __device__ __forceinline__ bf16x8 load8(const T* p);
template <> __device__ __forceinline__ bf16x8 load8<bf16_t>(const bf16_t* p) {
    return *(const bf16x8*)p;
}
template <> __device__ __forceinline__ bf16x8 load8<float>(const float* p) {
    f32x4 a = *(const f32x4*)p;
    f32x4 b = *(const f32x4*)(p + 4);
    bf16x8 r;
    r[0] = (bf16_t)a[0]; r[1] = (bf16_t)a[1]; r[2] = (bf16_t)a[2]; r[3] = (bf16_t)a[3];
    r[4] = (bf16_t)b[0]; r[5] = (bf16_t)b[1]; r[6] = (bf16_t)b[2]; r[7] = (bf16_t)b[3];
    return r;
}
template <typename T> __device__ __forceinline__ float ldf(const T* p) { return (float)*p; }
template <typename T> __device__ __forceinline__ void stf(T* p, float v) { *p = (T)v; }

struct SmemT {
    __align__(16) bf16_t xT[T_LEN][MT][LDSP];  // x tile, A-fragment layout
    __align__(16) bf16_t hA[2][2][MT][LDSP];   // [layer][buf][node][h]
    __align__(16) float  cwf[T_LEN][NHEADS * T_LEN];
    __align__(16) float  cbf[T_LEN];
};

template <typename TIN>
__device__ __forceinline__ void run_lstm(
    SmemT& s,
    const TIN* __restrict__ xg,   // (T, N, 64)
    const TIN* __restrict__ Wih,  // (2, 8, 256, 64)
    const TIN* __restrict__ Whh,  // (2, 8, 256, 64)
    const TIN* __restrict__ bih,  // (2, 8, 256)
    const TIN* __restrict__ bhh,  // (2, 8, 256)
    const TIN* __restrict__ h0g,  // (8, 2, N, 64)
    const TIN* __restrict__ c0g,  // (8, 2, N, 64)
    const TIN* __restrict__ cwg,  // (12, 96)
    const TIN* __restrict__ cbg,  // (12)
    TIN* __restrict__ outg)       // (12, N, 64)
{
    const int tid  = threadIdx.x;
    const int w    = tid >> 6;     // wave id: owns H-slice [16w, 16w+16)
    const int lane = tid & 63;
    const int quad = lane >> 4;
    const int col  = lane & 15;
    const int nb   = blockIdx.x * MT;

    // ---- one-time staging: x tile (12*16*64 elems, coalesced) ----
    #pragma unroll
    for (int it = 0; it < 6; ++it) {
        int ci   = it * 256 + tid;          // 8-elem chunk id, 1536 total
        int e    = ci * 8;
        int t    = e >> 10;
        int node = (e >> 6) & (MT - 1);
        int f    = e & (HD - 1);
        bf16x8 v = load8<TIN>(xg + ((size_t)t * NNODES + nb + node) * HD + f);
        *(bf16x8*)&s.xT[t][node][f] = v;
    }
    for (int i = tid; i < T_LEN * NHEADS * T_LEN; i += 256)
        s.cwf[i / 96][i % 96] = ldf(cwg + i);
    if (tid < T_LEN) s.cbf[tid] = ldf(cbg + tid);

    float conv_acc[T_LEN][4];
    #pragma unroll
    for (int o = 0; o < T_LEN; ++o)
        #pragma unroll
        for (int r = 0; r < 4; ++r) conv_acc[o][r] = 0.0f;

    #pragma unroll 1
    for (int a = 0; a < NHEADS; ++a) {
        // ---- per-head weight B-fragments, register-resident ----
        bf16x8 wih[2][4][2], whh[2][4][2];   // [layer][gate i/f/g/o][kfrag]
        #pragma unroll
        for (int l = 0; l < 2; ++l)
            #pragma unroll
            for (int ni = 0; ni < 4; ++ni)
                #pragma unroll
                for (int kf = 0; kf < 2; ++kf) {
                    size_t off = (((size_t)l * NHEADS + a) * 256 + (4 * ni + w) * 16 + col) * HD
                               + kf * 32 + quad * 8;
                    wih[l][ni][kf] = load8<TIN>(Wih + off);
                    whh[l][ni][kf] = load8<TIN>(Whh + off);
                }
        float bias[2][4];
        #pragma unroll
        for (int l = 0; l < 2; ++l)
            #pragma unroll
            for (int ni = 0; ni < 4; ++ni) {
                int off = (l * NHEADS + a) * 256 + ni * 64 + w * 16 + col;
                bias[l][ni] = ldf(bih + off) + ldf(bhh + off);
            }
        float creg[2][4];
        #pragma unroll
        for (int l = 0; l < 2; ++l)
            #pragma unroll
            for (int r = 0; r < 4; ++r)
                creg[l][r] = ldf(c0g + (((size_t)a * 2 + l) * NNODES + nb + quad * 4 + r) * HD
                                     + w * 16 + col);
        // h0 -> hA[*][0]  (2048 elems, one 8-elem chunk per thread). The
        // trailing __syncthreads of the previous head's last step orders this.
        {
            int e    = tid * 8;
            int l    = e >> 10;
            int node = (e >> 6) & (MT - 1);
            int hh   = e & (HD - 1);
            bf16x8 v = load8<TIN>(h0g + (((size_t)a * 2 + l) * NNODES + nb + node) * HD + hh);
            *(bf16x8*)&s.hA[l][0][node][hh] = v;
        }
        __syncthreads();

        int cur = 0;
        #pragma unroll 1
        for (int t = 0; t < T_LEN; ++t) {
            // ---------- layer 0: gates = x_t*Wih0^T + h0*Whh0^T ----------
            bf16x8 xa0 = *(const bf16x8*)&s.xT[t][col][quad * 8];
            bf16x8 xa1 = *(const bf16x8*)&s.xT[t][col][32 + quad * 8];
            bf16x8 ha0 = *(const bf16x8*)&s.hA[0][cur][col][quad * 8];
            bf16x8 ha1 = *(const bf16x8*)&s.hA[0][cur][col][32 + quad * 8];
            f32x4 acc[4];
            #pragma unroll
            for (int ni = 0; ni < 4; ++ni) {
                f32x4 z = {0.f, 0.f, 0.f, 0.f};
                z = MFMA16(xa0, wih[0][ni][0], z);
                z = MFMA16(xa1, wih[0][ni][1], z);
                z = MFMA16(ha0, whh[0][ni][0], z);
                z = MFMA16(ha1, whh[0][ni][1], z);
                acc[ni] = z;
            }
            #pragma unroll
            for (int r = 0; r < 4; ++r) {
                float ig = fast_sigmoid(acc[0][r] + bias[0][0]);
                float fg = fast_sigmoid(acc[1][r] + bias[0][1]);
                float gg = fast_tanh   (acc[2][r] + bias[0][2]);
                float og = fast_sigmoid(acc[3][r] + bias[0][3]);
                float cn = fg * creg[0][r] + ig * gg;
                creg[0][r] = cn;
                s.hA[0][cur ^ 1][quad * 4 + r][w * 16 + col] = (bf16_t)(og * fast_tanh(cn));
            }
            __syncthreads();
            // ---------- layer 1: gates = h0'*Wih1^T + h1*Whh1^T ----------
            bf16x8 pa0 = *(const bf16x8*)&s.hA[0][cur ^ 1][col][quad * 8];
            bf16x8 pa1 = *(const bf16x8*)&s.hA[0][cur ^ 1][col][32 + quad * 8];
            bf16x8 qa0 = *(const bf16x8*)&s.hA[1][cur][col][quad * 8];
            bf16x8 qa1 = *(const bf16x8*)&s.hA[1][cur][col][32 + quad * 8];
            #pragma unroll
            for (int ni = 0; ni < 4; ++ni) {
                f32x4 z = {0.f, 0.f, 0.f, 0.f};
                z = MFMA16(pa0, wih[1][ni][0], z);
                z = MFMA16(pa1, wih[1][ni][1], z);
                z = MFMA16(qa0, whh[1][ni][0], z);
                z = MFMA16(qa1, whh[1][ni][1], z);
                acc[ni] = z;
            }
            float hn[4];
            #pragma unroll
            for (int r = 0; r < 4; ++r) {
                float ig = fast_sigmoid(acc[0][r] + bias[1][0]);
                float fg = fast_sigmoid(acc[1][r] + bias[1][1]);
                float gg = fast_tanh   (acc[2][r] + bias[1][2]);
                float og = fast_sigmoid(acc[3][r] + bias[1][3]);
                float cn = fg * creg[1][r] + ig * gg;
                creg[1][r] = cn;
                hn[r] = og * fast_tanh(cn);
                s.hA[1][cur ^ 1][quad * 4 + r][w * 16 + col] = (bf16_t)hn[r];
            }
            // conv accumulation: channel c = a*12 + t  (cat is head-major)
            #pragma unroll
            for (int o = 0; o < T_LEN; ++o) {
                float cv = s.cwf[o][a * T_LEN + t];
                #pragma unroll
                for (int r = 0; r < 4; ++r) conv_acc[o][r] += cv * hn[r];
            }
            __syncthreads();
            cur ^= 1;
        }
    }
    // ---- epilogue: conv bias + store (every out element written once) ----
    #pragma unroll
    for (int o = 0; o < T_LEN; ++o)
        #pragma unroll
        for (int r = 0; r < 4; ++r)
            stf(outg + ((size_t)o * NNODES + nb + quad * 4 + r) * HD + w * 16 + col,
                conv_acc[o][r] + s.cbf[o]);
}

// 1-thread dtype detector: bf16-interpret the first 256 half-words of x.
// Sane bf16 data (x ~ N(0,1)) has exponent fields <= ~0x82; fp32 low
// half-words have uniform-random exponent fields (~44% >= 0x90). flag=1 -> fp32.
__global__ void detect_dtype_kernel(const unsigned short* __restrict__ x,
                                    int* __restrict__ flag) {
    if (threadIdx.x == 0 && blockIdx.x == 0) {
        int bad = 0;
        for (int i = 0; i < 256; ++i) {
            int e = (x[i] >> 7) & 0xFF;
            bad += (e >= 0x90) ? 1 : 0;
        }
        *flag = (bad > 8) ? 1 : 0;
    }
}

__global__ __launch_bounds__(256) void lstm_fused_kernel(
    const void* xg, const void* Wih, const void* Whh, const void* bih,
    const void* bhh, const void* h0g, const void* c0g, const void* cwg,
    const void* cbg, void* outg, const int* __restrict__ flag)
{
    __shared__ SmemT s;
    if (*flag) {
        run_lstm<float>(s, (const float*)xg, (const float*)Wih, (const float*)Whh,
                        (const float*)bih, (const float*)bhh, (const float*)h0g,
                        (const float*)c0g, (const float*)cwg, (const float*)cbg,
                        (float*)outg);
    } else {
        run_lstm<bf16_t>(s, (const bf16_t*)xg, (const bf16_t*)Wih, (const bf16_t*)Whh,
                         (const bf16_t*)bih, (const bf16_t*)bhh, (const bf16_t*)h0g,
                         (const bf16_t*)c0g, (const bf16_t*)cwg, (const bf16_t*)cbg,
                         (bf16_t*)outg);
    }
}

extern "C" void kernel_launch(void* const* d_in, const int* in_sizes, int n_in,
                              void* d_out, int out_size, void* d_ws, size_t ws_size,
                              hipStream_t stream) {
    (void)in_sizes; (void)n_in; (void)ws_size; (void)out_size;
    int* flag = (int*)d_ws;
    detect_dtype_kernel<<<dim3(1), dim3(64), 0, stream>>>(
        (const unsigned short*)d_in[0], flag);
    lstm_fused_kernel<<<dim3(NNODES / MT), dim3(256), 0, stream>>>(
        d_in[0], d_in[1], d_in[2], d_in[3], d_in[4], d_in[5], d_in[6],
        d_in[7], d_in[8], d_out, flag);
}